// Round 6
// baseline (182.176 us; speedup 1.0000x reference)
//
#include <hip/hip_runtime.h>
#include <hip/hip_bf16.h>

// EdgePredictor: out[e] = relu(concat(X[row], X[col]) @ W1 + b1) @ W2 + b2
// Precompute per-node AB[n][256] = {X[n]@W1[:128,:] | X[n]@W1[128:,:]} in f16.
// Per edge: out = relu(A[row] + B[col] + b1) @ W2 + b2.
//
// R6 (single-variable: edge phase only): edge_mlp was miss-latency bound
// (all pipes <35%, ~4M random 64B lines x ~650cyc blended latency, MSHR-
// capped — explains R3->R4 neutrality). New: bucket edges by row into 32
// row-ranges (1.6MB of AB rows each) so the active A-row window is
// XCD-L2-resident; waves process buckets in order. Scatter kernel packs
// (eid|row|col) in u64, LDS-histogram + one global atomicAdd per bucket per
// block. gemm_ab/prep unchanged from R5 (prep additionally zeros cursors).

#define EMBED 128
#define NBUK 32
#define BCAP 18432  // slots/bucket, multiple of 128; avg fill 15625 (+22 sigma safe)

typedef _Float16 half8 __attribute__((ext_vector_type(8)));
typedef _Float16 half4 __attribute__((ext_vector_type(4)));
typedef float floatx4 __attribute__((ext_vector_type(4)));
typedef unsigned long long u64;
typedef unsigned int u32;

// --- Kernel 0: fused prep.
// Blocks 0..127: transpose+convert W1 (256x128 f32) -> WT (256x128 f16).
// Block 128: idx-mode ballot detect; W2PT[16][128] f16; b1f[128] f16;
//            zero the 32 bucket cursors (ws is poisoned 0xAA every launch).
__global__ __launch_bounds__(256) void prep(
    const float* __restrict__ W1, const float* __restrict__ W2,
    const float* __restrict__ b1, const int* __restrict__ idx,
    _Float16* __restrict__ WT, _Float16* __restrict__ W2PT,
    _Float16* __restrict__ b1f, int* __restrict__ flag, u32* __restrict__ cur) {
    if (blockIdx.x < 128) {
        __shared__ float lds[16][17];
        const int ty = threadIdx.x >> 4, tx = threadIdx.x & 15;
        const int r0 = (blockIdx.x >> 3) * 16;   // source W1 row tile
        const int c0 = (blockIdx.x & 7) * 16;    // source W1 col tile
        lds[ty][tx] = W1[(r0 + ty) * 128 + c0 + tx];
        __syncthreads();
        const int jbase = c0 + (r0 >= 128 ? 128 : 0);
        const int kbase = r0 & 127;
        WT[(size_t)(jbase + ty) * 128 + kbase + tx] = (_Float16)lds[tx][ty];
    } else {
        const int t = threadIdx.x;
        if (t < 64) {  // int64 layout iff first 64 high words are all zero
            const int hw = idx[2 * t + 1];
            const unsigned long long m = __ballot(hw != 0);
            if (t == 0) *flag = (m == 0ull) ? 1 : 0;
        }
        if (t < NBUK) cur[t] = 0;
        if (t < 128) b1f[t] = (_Float16)b1[t];
        for (int i = t; i < 2048; i += 256) {  // W2PT[n][k] = n<2 ? W2[k][n] : 0
            const int n = i >> 7, k = i & 127;
            W2PT[i] = (n < 2) ? (_Float16)W2[k * 2 + n] : (_Float16)0.f;
        }
    }
}

// --- Kernel 1: bucket edges by row range. Packs (eid[19b]|row[17b]|col[17b])
// into u64. Per 256-edge chunk: LDS hist -> 1 global atomicAdd per bucket ->
// LDS-cursor scatter (avoids 500K same-line global atomics).
__global__ __launch_bounds__(256) void scatter_edges(
    const int* __restrict__ eidx, const int* __restrict__ flag,
    u32* __restrict__ cur, u64* __restrict__ buckets,
    int n_edges, int n_nodes) {
    __shared__ u32 hist[NBUK], base[NBUK], lcur[NBUK];
    const int t = threadIdx.x;
    const int mode = *flag;
    const int bw = (n_nodes + NBUK - 1) / NBUK;
    const int nchunks = (n_edges + 255) / 256;
    for (int c = blockIdx.x; c < nchunks; c += gridDim.x) {
        const int e = c * 256 + t;
        const bool valid = e < n_edges;
        const int ec = valid ? e : 0;
        int row, col;
        if (mode) {  // int64 layout: low word at int32 index 2*k
            row = eidx[2 * (size_t)ec];
            col = eidx[2 * ((size_t)n_edges + ec)];
        } else {
            row = eidx[ec];
            col = eidx[(size_t)n_edges + ec];
        }
        const int b = row / bw;
        if (t < NBUK) hist[t] = 0;
        __syncthreads();
        if (valid) atomicAdd(&hist[b], 1u);
        __syncthreads();
        if (t < NBUK) { base[t] = atomicAdd(&cur[t], hist[t]); lcur[t] = 0; }
        __syncthreads();
        if (valid) {
            const u32 s = base[b] + atomicAdd(&lcur[b], 1u);
            if (s < BCAP)
                buckets[(size_t)b * BCAP + s] =
                    (u64)(u32)ec | ((u64)(u32)row << 19) | ((u64)(u32)col << 36);
        }
        __syncthreads();  // protect hist/lcur before next chunk
    }
}

// --- Kernel 2: AB = [X | X] @ Wcat via f16 MFMA, operand-swapped
// (A-operand = W-frag so D rows are output cols). Grid-stride over 64-node
// tiles; 4 waves, wave w covers output cols [w*64, w*64+64).
// Epilogue: D-frags -> padded LDS tile -> fully coalesced b128 stores.
__global__ __launch_bounds__(256) void gemm_ab(
    const float* __restrict__ X, const _Float16* __restrict__ WT,
    _Float16* __restrict__ AB, int n_nodes, int n_tiles) {
    __shared__ _Float16 xs[64 * 136];    // 17408 B staging, stride 136
    __shared__ _Float16 outs[64 * 264];  // 33792 B out tile, stride 264
    const int t = threadIdx.x;
    const int w = t >> 6, lane = t & 63, lm = lane & 15, quad = lane >> 4;

    for (int T = blockIdx.x; T < n_tiles; T += gridDim.x) {
        const int mblk = T * 64;

#pragma unroll
        for (int i = 0; i < 8; ++i) {
            const int flat = i * 1024 + t * 4;  // float index in 64x128 tile
            const int row = flat >> 7, col = flat & 127;
            int node = mblk + row;
            if (node > n_nodes - 1) node = n_nodes - 1;  // clamp; never stored
            const float4 v = *(const float4*)(X + (size_t)node * EMBED + col);
            half4 h;
            h[0] = (_Float16)v.x; h[1] = (_Float16)v.y;
            h[2] = (_Float16)v.z; h[3] = (_Float16)v.w;
            *(half4*)(xs + row * 136 + col) = h;
        }
        __syncthreads();

        floatx4 acc[4][4];  // [mf: node tile][jf: col tile]
#pragma unroll
        for (int a = 0; a < 4; ++a)
#pragma unroll
            for (int b = 0; b < 4; ++b)
                acc[a][b] = (floatx4){0.f, 0.f, 0.f, 0.f};

#pragma unroll
        for (int ks = 0; ks < 4; ++ks) {
            const int k0 = ks * 32 + quad * 8;
            half8 xf[4];  // B-operand: B[k][n=lane&15] = Xf16[node mf*16+lm][k]
#pragma unroll
            for (int mf = 0; mf < 4; ++mf)
                xf[mf] = *(const half8*)(xs + (mf * 16 + lm) * 136 + k0);
#pragma unroll
            for (int jf = 0; jf < 4; ++jf) {
                const int j = w * 64 + jf * 16 + lm;  // A-op: WT row = out col
                const half8 wf = *(const half8*)(WT + (size_t)j * EMBED + k0);
#pragma unroll
                for (int mf = 0; mf < 4; ++mf)
                    acc[mf][jf] = __builtin_amdgcn_mfma_f32_16x16x32_f16(wf, xf[mf], acc[mf][jf], 0, 0, 0);
            }
        }

        // Pack D into LDS out tile: node-major [local node][j], stride 264.
#pragma unroll
        for (int mf = 0; mf < 4; ++mf) {
#pragma unroll
            for (int jf = 0; jf < 4; ++jf) {
                half4 h;
#pragma unroll
                for (int r = 0; r < 4; ++r) h[r] = (_Float16)acc[mf][jf][r];
                *(half4*)(outs + (mf * 16 + lm) * 264 + w * 64 + jf * 16 + quad * 4) = h;
            }
        }
        __syncthreads();

        // Coalesced store: 64 nodes x 512 B contiguous in AB (node-major).
#pragma unroll
        for (int i = 0; i < 8; ++i) {
            const int idx8 = i * 256 + t;         // half8 index in 64x256 tile
            const int node = idx8 >> 5, jj = idx8 & 31;
            if (mblk + node < n_nodes)
                *(half8*)(AB + (size_t)(mblk + node) * 256 + jj * 8) =
                    *(const half8*)(outs + node * 264 + jj * 8);
        }
        __syncthreads();
    }
}

// --- Kernel 3: per-edge MLP over bucketed slots, 32 edges/wave (2 MFMA
// groups). Blocks ascend through buckets so the active A-row window
// (~2 buckets = 3.2 MB of AB) stays XCD-L2-resident.
__global__ __launch_bounds__(256) void edge_mlp(
    const _Float16* __restrict__ AB, const u64* __restrict__ buckets,
    const u32* __restrict__ cnt, const _Float16* __restrict__ b1f,
    const _Float16* __restrict__ W2PT, const float* __restrict__ b2,
    float* __restrict__ out, int n_edges) {
    const int lane = threadIdx.x & 63, lm = lane & 15, quad = lane >> 4;
    const int sbase = (blockIdx.x * 4 + (threadIdx.x >> 6)) * 32;  // slot base
    const int bucket = sbase / BCAP;       // BCAP % 128 == 0: no straddle
    const u32 bcnt = cnt[bucket];
    const int boff = sbase - bucket * BCAP;
    if ((u32)boff >= bcnt) return;         // wave entirely past bucket fill
    const int end = bucket * BCAP + (int)(bcnt < BCAP ? bcnt : BCAP);

    const int s0 = sbase + lm, s1 = sbase + 16 + lm;
    const bool v0 = s0 < end, v1 = s1 < end;
    const u64 p0 = buckets[v0 ? s0 : sbase];
    const u64 p1 = buckets[v1 ? s1 : sbase];
    const int row0 = v0 ? (int)((p0 >> 19) & 0x1FFFF) : 0;
    const int col0 = v0 ? (int)((p0 >> 36) & 0x1FFFF) : 0;
    const int row1 = v1 ? (int)((p1 >> 19) & 0x1FFFF) : 0;
    const int col1 = v1 ? (int)((p1 >> 36) & 0x1FFFF) : 0;

    const _Float16* a0p = AB + (size_t)row0 * 256;
    const _Float16* b0p = AB + (size_t)col0 * 256 + 128;
    const _Float16* a1p = AB + (size_t)row1 * 256;
    const _Float16* b1p = AB + (size_t)col1 * 256 + 128;

    // Issue all 16 gathers up front (each b128: 16 rows x 64B contiguous).
    half8 a0[4], b0[4], a1[4], b1[4];
#pragma unroll
    for (int ks = 0; ks < 4; ++ks) {
        const int k0 = ks * 32 + quad * 8;
        a0[ks] = *(const half8*)(a0p + k0);
        b0[ks] = *(const half8*)(b0p + k0);
        a1[ks] = *(const half8*)(a1p + k0);
        b1[ks] = *(const half8*)(b1p + k0);
    }

    floatx4 acc0 = (floatx4){0.f, 0.f, 0.f, 0.f};
    floatx4 acc1 = (floatx4){0.f, 0.f, 0.f, 0.f};
#pragma unroll
    for (int ks = 0; ks < 4; ++ks) {
        const int k0 = ks * 32 + quad * 8;
        const half8 bi = *(const half8*)(b1f + k0);          // wave-uniform
        const half8 wv = *(const half8*)(W2PT + lm * 128 + k0);
        half8 h0 = a0[ks] + b0[ks] + bi;
        half8 h1 = a1[ks] + b1[ks] + bi;
#pragma unroll
        for (int j = 0; j < 8; ++j) {
            h0[j] = h0[j] > (_Float16)0.f ? h0[j] : (_Float16)0.f;
            h1[j] = h1[j] > (_Float16)0.f ? h1[j] : (_Float16)0.f;
        }
        acc0 = __builtin_amdgcn_mfma_f32_16x16x32_f16(h0, wv, acc0, 0, 0, 0);
        acc1 = __builtin_amdgcn_mfma_f32_16x16x32_f16(h1, wv, acc1, 0, 0, 0);
    }

    // D rows (quad*4+r) = edge-in-group; recover eid from the slot table
    // (L1-hot) and scatter-store out[eid].
    if (lm < 2) {
        const float b2v = b2[lm];
#pragma unroll
        for (int r = 0; r < 4; ++r) {
            const int sa = sbase + quad * 4 + r;
            if (sa < end) {
                const int eid = (int)(buckets[sa] & 0x7FFFF);
                out[(size_t)eid * 2 + lm] = acc0[r] + b2v;
            }
            const int sb = sbase + 16 + quad * 4 + r;
            if (sb < end) {
                const int eid = (int)(buckets[sb] & 0x7FFFF);
                out[(size_t)eid * 2 + lm] = acc1[r] + b2v;
            }
        }
    }
}

extern "C" void kernel_launch(void* const* d_in, const int* in_sizes, int n_in,
                              void* d_out, int out_size, void* d_ws, size_t ws_size,
                              hipStream_t stream) {
    const float* X   = (const float*)d_in[0];
    const int*   idx = (const int*)d_in[1];
    const float* W1  = (const float*)d_in[2];
    const float* b1  = (const float*)d_in[3];
    const float* W2  = (const float*)d_in[4];
    const float* b2  = (const float*)d_in[5];
    float* out = (float*)d_out;

    const int n_nodes = in_sizes[0] / EMBED;   // 100000
    const int n_edges = in_sizes[1] / 2;       // 500000

    // ws: flag @0 | cur @64 (32*u32) | AB @256 (51.2MB) | WT (64KB) |
    //     W2PT (4KB) | b1f (256B) | buckets (32*18432*8 = 4.7MB)  ~= 56MB
    char* ws = (char*)d_ws;
    int*      flag = (int*)ws;
    u32*      cur  = (u32*)(ws + 64);
    _Float16* AB   = (_Float16*)(ws + 256);
    _Float16* WT   = (_Float16*)(ws + 256 + (size_t)n_nodes * 512);
    _Float16* W2PT = WT + 256 * 128;
    _Float16* b1f  = W2PT + 16 * 128;
    u64*      buckets = (u64*)((char*)(b1f + 256));

    const int n_tiles = (n_nodes + 63) / 64;   // 1563

    prep<<<129, 256, 0, stream>>>(W1, W2, b1, idx, WT, W2PT, b1f, flag, cur);
    scatter_edges<<<512, 256, 0, stream>>>(idx, flag, cur, buckets, n_edges, n_nodes);
    gemm_ab<<<782, 256, 0, stream>>>(X, WT, AB, n_nodes, n_tiles);
    edge_mlp<<<(NBUK * BCAP) / 128, 256, 0, stream>>>(
        AB, buckets, cur, b1f, W2PT, b2, out, n_edges);
}

// Round 7
// 173.979 us; speedup vs baseline: 1.0471x; 1.0471x over previous
//
#include <hip/hip_runtime.h>
#include <hip/hip_bf16.h>

// EdgePredictor: out[e] = relu(concat(X[row], X[col]) @ W1 + b1) @ W2 + b2
// Precompute per-node AB[n][256] = {X[n]@W1[:128,:] | X[n]@W1[128:,:]} in f16.
// Per edge: out = relu(A[row] + B[col] + b1) @ W2 + b2.
//
// R7 (edge path only; gemm/prep-W unchanged): R6 post-mortem showed (a)
// scatter's 28us was same-line global atomics (62K adds on 2 cache lines),
// (b) 32 buckets gave no locality (8MB active window > 4MiB XCD L2).
// Now: 256 buckets (100KB A-slice each, ~5x row reuse inside a bucket ->
// A-half L2-hits), scatter v2 = contiguous chunk/block, 2-pass LDS
// histogram + ONE atomic per bucket per block onto 64B-padded counters.

#define EMBED 128
#define NBUK 256
#define BCAP 2304   // 18*128: no wave straddle; avg fill 1953, +8 sigma
#define CURSTRIDE 16  // u32s; one counter per 64B line

typedef _Float16 half8 __attribute__((ext_vector_type(8)));
typedef _Float16 half4 __attribute__((ext_vector_type(4)));
typedef float floatx4 __attribute__((ext_vector_type(4)));
typedef unsigned long long u64;
typedef unsigned int u32;

// --- Kernel 0: fused prep.
// Blocks 0..127: transpose+convert W1 (256x128 f32) -> WT (256x128 f16).
// Block 128: idx-mode ballot detect; W2PT[16][128] f16; b1f[128] f16;
//            zero the padded bucket cursors (ws is poisoned 0xAA).
__global__ __launch_bounds__(256) void prep(
    const float* __restrict__ W1, const float* __restrict__ W2,
    const float* __restrict__ b1, const int* __restrict__ idx,
    _Float16* __restrict__ WT, _Float16* __restrict__ W2PT,
    _Float16* __restrict__ b1f, int* __restrict__ flag, u32* __restrict__ cur) {
    if (blockIdx.x < 128) {
        __shared__ float lds[16][17];
        const int ty = threadIdx.x >> 4, tx = threadIdx.x & 15;
        const int r0 = (blockIdx.x >> 3) * 16;   // source W1 row tile
        const int c0 = (blockIdx.x & 7) * 16;    // source W1 col tile
        lds[ty][tx] = W1[(r0 + ty) * 128 + c0 + tx];
        __syncthreads();
        const int jbase = c0 + (r0 >= 128 ? 128 : 0);
        const int kbase = r0 & 127;
        WT[(size_t)(jbase + ty) * 128 + kbase + tx] = (_Float16)lds[tx][ty];
    } else {
        const int t = threadIdx.x;
        if (t < 64) {  // int64 layout iff first 64 high words are all zero
            const int hw = idx[2 * t + 1];
            const unsigned long long m = __ballot(hw != 0);
            if (t == 0) *flag = (m == 0ull) ? 1 : 0;
        }
        for (int i = t; i < NBUK * CURSTRIDE; i += 256) cur[i] = 0;
        if (t < 128) b1f[t] = (_Float16)b1[t];
        for (int i = t; i < 2048; i += 256) {  // W2PT[n][k] = n<2 ? W2[k][n] : 0
            const int n = i >> 7, k = i & 127;
            W2PT[i] = (n < 2) ? (_Float16)W2[k * 2 + n] : (_Float16)0.f;
        }
    }
}

// --- Kernel 1: bucket edges by row range (256 buckets). Each block owns a
// contiguous edge chunk; pass 1 LDS-histograms it, then ONE global atomicAdd
// per touched bucket (counters 64B-padded -> no same-line serialization),
// pass 2 scatters via LDS cursors. Packs (eid[19b]|row[17b]|col[17b]) u64.
__global__ __launch_bounds__(256) void scatter_edges(
    const int* __restrict__ eidx, const int* __restrict__ flag,
    u32* __restrict__ cur, u64* __restrict__ buckets,
    int n_edges, int n_nodes, int per_block) {
    __shared__ u32 hist[NBUK], base[NBUK];
    const int t = threadIdx.x;
    const int mode = *flag;
    const int bw = (n_nodes + NBUK - 1) / NBUK;
    const int start = blockIdx.x * per_block;
    const int end = min(start + per_block, n_edges);
    if (start >= n_edges) return;

    if (t < NBUK) hist[t] = 0;
    __syncthreads();
    for (int e = start + t; e < end; e += 256) {
        const int row = mode ? eidx[2 * (size_t)e] : eidx[e];
        atomicAdd(&hist[row / bw], 1u);
    }
    __syncthreads();
    if (t < NBUK) {
        const u32 h = hist[t];
        base[t] = h ? atomicAdd(&cur[t * CURSTRIDE], h) : 0u;
        hist[t] = 0;  // reuse as running cursor
    }
    __syncthreads();
    for (int e = start + t; e < end; e += 256) {
        int row, col;
        if (mode) {  // int64 layout: low word at int32 index 2*k
            row = eidx[2 * (size_t)e];
            col = eidx[2 * ((size_t)n_edges + e)];
        } else {
            row = eidx[e];
            col = eidx[(size_t)n_edges + e];
        }
        const int b = row / bw;
        const u32 s = base[b] + atomicAdd(&hist[b], 1u);
        if (s < BCAP)
            buckets[(size_t)b * BCAP + s] =
                (u64)(u32)e | ((u64)(u32)row << 19) | ((u64)(u32)col << 36);
    }
}

// --- Kernel 2: AB = [X | X] @ Wcat via f16 MFMA, operand-swapped
// (A-operand = W-frag so D rows are output cols). Grid-stride over 64-node
// tiles; 4 waves, wave w covers output cols [w*64, w*64+64).
// Epilogue: D-frags -> padded LDS tile -> fully coalesced b128 stores.
__global__ __launch_bounds__(256) void gemm_ab(
    const float* __restrict__ X, const _Float16* __restrict__ WT,
    _Float16* __restrict__ AB, int n_nodes, int n_tiles) {
    __shared__ _Float16 xs[64 * 136];    // 17408 B staging, stride 136
    __shared__ _Float16 outs[64 * 264];  // 33792 B out tile, stride 264
    const int t = threadIdx.x;
    const int w = t >> 6, lane = t & 63, lm = lane & 15, quad = lane >> 4;

    for (int T = blockIdx.x; T < n_tiles; T += gridDim.x) {
        const int mblk = T * 64;

#pragma unroll
        for (int i = 0; i < 8; ++i) {
            const int flat = i * 1024 + t * 4;  // float index in 64x128 tile
            const int row = flat >> 7, col = flat & 127;
            int node = mblk + row;
            if (node > n_nodes - 1) node = n_nodes - 1;  // clamp; never stored
            const float4 v = *(const float4*)(X + (size_t)node * EMBED + col);
            half4 h;
            h[0] = (_Float16)v.x; h[1] = (_Float16)v.y;
            h[2] = (_Float16)v.z; h[3] = (_Float16)v.w;
            *(half4*)(xs + row * 136 + col) = h;
        }
        __syncthreads();

        floatx4 acc[4][4];  // [mf: node tile][jf: col tile]
#pragma unroll
        for (int a = 0; a < 4; ++a)
#pragma unroll
            for (int b = 0; b < 4; ++b)
                acc[a][b] = (floatx4){0.f, 0.f, 0.f, 0.f};

#pragma unroll
        for (int ks = 0; ks < 4; ++ks) {
            const int k0 = ks * 32 + quad * 8;
            half8 xf[4];  // B-operand: B[k][n=lane&15] = Xf16[node mf*16+lm][k]
#pragma unroll
            for (int mf = 0; mf < 4; ++mf)
                xf[mf] = *(const half8*)(xs + (mf * 16 + lm) * 136 + k0);
#pragma unroll
            for (int jf = 0; jf < 4; ++jf) {
                const int j = w * 64 + jf * 16 + lm;  // A-op: WT row = out col
                const half8 wf = *(const half8*)(WT + (size_t)j * EMBED + k0);
#pragma unroll
                for (int mf = 0; mf < 4; ++mf)
                    acc[mf][jf] = __builtin_amdgcn_mfma_f32_16x16x32_f16(wf, xf[mf], acc[mf][jf], 0, 0, 0);
            }
        }

        // Pack D into LDS out tile: node-major [local node][j], stride 264.
#pragma unroll
        for (int mf = 0; mf < 4; ++mf) {
#pragma unroll
            for (int jf = 0; jf < 4; ++jf) {
                half4 h;
#pragma unroll
                for (int r = 0; r < 4; ++r) h[r] = (_Float16)acc[mf][jf][r];
                *(half4*)(outs + (mf * 16 + lm) * 264 + w * 64 + jf * 16 + quad * 4) = h;
            }
        }
        __syncthreads();

        // Coalesced store: 64 nodes x 512 B contiguous in AB (node-major).
#pragma unroll
        for (int i = 0; i < 8; ++i) {
            const int idx8 = i * 256 + t;         // half8 index in 64x256 tile
            const int node = idx8 >> 5, jj = idx8 & 31;
            if (mblk + node < n_nodes)
                *(half8*)(AB + (size_t)(mblk + node) * 256 + jj * 8) =
                    *(const half8*)(outs + node * 264 + jj * 8);
        }
        __syncthreads();
    }
}

// --- Kernel 3: per-edge MLP over bucketed slots, 32 edges/wave (2 MFMA
// groups). Bucket A-slices are ~100KB; the concurrently-active window per
// XCD stays L2-resident, and avg row degree 5 gives ~5x A-line reuse.
__global__ __launch_bounds__(256) void edge_mlp(
    const _Float16* __restrict__ AB, const u64* __restrict__ buckets,
    const u32* __restrict__ cur, const _Float16* __restrict__ b1f,
    const _Float16* __restrict__ W2PT, const float* __restrict__ b2,
    float* __restrict__ out, int n_edges) {
    const int lane = threadIdx.x & 63, lm = lane & 15, quad = lane >> 4;
    const int sbase = (blockIdx.x * 4 + (threadIdx.x >> 6)) * 32;  // slot base
    const int bucket = sbase / BCAP;       // BCAP % 128 == 0: no straddle
    const u32 bcnt = cur[bucket * CURSTRIDE];
    const int boff = sbase - bucket * BCAP;
    if ((u32)boff >= bcnt) return;         // wave entirely past bucket fill
    const int end = bucket * BCAP + (int)(bcnt < BCAP ? bcnt : BCAP);

    const int s0 = sbase + lm, s1 = sbase + 16 + lm;
    const bool v0 = s0 < end, v1 = s1 < end;
    const u64 p0 = buckets[v0 ? s0 : sbase];
    const u64 p1 = buckets[v1 ? s1 : sbase];
    const int row0 = (int)((p0 >> 19) & 0x1FFFF);
    const int col0 = (int)((p0 >> 36) & 0x1FFFF);
    const int row1 = (int)((p1 >> 19) & 0x1FFFF);
    const int col1 = (int)((p1 >> 36) & 0x1FFFF);

    const _Float16* a0p = AB + (size_t)row0 * 256;
    const _Float16* b0p = AB + (size_t)col0 * 256 + 128;
    const _Float16* a1p = AB + (size_t)row1 * 256;
    const _Float16* b1p = AB + (size_t)col1 * 256 + 128;

    // Issue all 16 gathers up front (each b128: 16 edges x one 64B line).
    half8 a0[4], b0[4], a1[4], b1[4];
#pragma unroll
    for (int ks = 0; ks < 4; ++ks) {
        const int k0 = ks * 32 + quad * 8;
        a0[ks] = *(const half8*)(a0p + k0);
        b0[ks] = *(const half8*)(b0p + k0);
        a1[ks] = *(const half8*)(a1p + k0);
        b1[ks] = *(const half8*)(b1p + k0);
    }

    floatx4 acc0 = (floatx4){0.f, 0.f, 0.f, 0.f};
    floatx4 acc1 = (floatx4){0.f, 0.f, 0.f, 0.f};
#pragma unroll
    for (int ks = 0; ks < 4; ++ks) {
        const int k0 = ks * 32 + quad * 8;
        const half8 bi = *(const half8*)(b1f + k0);          // wave-uniform
        const half8 wv = *(const half8*)(W2PT + lm * 128 + k0);
        half8 h0 = a0[ks] + b0[ks] + bi;
        half8 h1 = a1[ks] + b1[ks] + bi;
#pragma unroll
        for (int j = 0; j < 8; ++j) {
            h0[j] = h0[j] > (_Float16)0.f ? h0[j] : (_Float16)0.f;
            h1[j] = h1[j] > (_Float16)0.f ? h1[j] : (_Float16)0.f;
        }
        acc0 = __builtin_amdgcn_mfma_f32_16x16x32_f16(h0, wv, acc0, 0, 0, 0);
        acc1 = __builtin_amdgcn_mfma_f32_16x16x32_f16(h1, wv, acc1, 0, 0, 0);
    }

    // D rows (quad*4+r) = edge-in-group; recover eid from the slot table
    // (L1-hot) and scatter-store out[eid].
    if (lm < 2) {
        const float b2v = b2[lm];
#pragma unroll
        for (int r = 0; r < 4; ++r) {
            const int sa = sbase + quad * 4 + r;
            if (sa < end) {
                const int eid = (int)(buckets[sa] & 0x7FFFF);
                out[(size_t)eid * 2 + lm] = acc0[r] + b2v;
            }
            const int sb = sbase + 16 + quad * 4 + r;
            if (sb < end) {
                const int eid = (int)(buckets[sb] & 0x7FFFF);
                out[(size_t)eid * 2 + lm] = acc1[r] + b2v;
            }
        }
    }
}

extern "C" void kernel_launch(void* const* d_in, const int* in_sizes, int n_in,
                              void* d_out, int out_size, void* d_ws, size_t ws_size,
                              hipStream_t stream) {
    const float* X   = (const float*)d_in[0];
    const int*   idx = (const int*)d_in[1];
    const float* W1  = (const float*)d_in[2];
    const float* b1  = (const float*)d_in[3];
    const float* W2  = (const float*)d_in[4];
    const float* b2  = (const float*)d_in[5];
    float* out = (float*)d_out;

    const int n_nodes = in_sizes[0] / EMBED;   // 100000
    const int n_edges = in_sizes[1] / 2;       // 500000

    // ws: flag @0 | cur @256 (256 ctrs x 64B = 16KB) | AB (51.2MB) |
    //     WT (64KB) | W2PT (4KB) | b1f (256B) | buckets (256*2304*8 = 4.7MB)
    char* ws = (char*)d_ws;
    int*      flag = (int*)ws;
    u32*      cur  = (u32*)(ws + 256);
    _Float16* AB   = (_Float16*)(ws + 256 + NBUK * CURSTRIDE * 4);
    _Float16* WT   = AB + (size_t)n_nodes * 256;
    _Float16* W2PT = WT + 256 * 128;
    _Float16* b1f  = W2PT + 16 * 128;
    u64*      buckets = (u64*)(b1f + 256);

    const int n_tiles = (n_nodes + 63) / 64;   // 1563
    const int sblocks = 256;
    const int per_block = (n_edges + sblocks - 1) / sblocks;

    prep<<<129, 256, 0, stream>>>(W1, W2, b1, idx, WT, W2PT, b1f, flag, cur);
    scatter_edges<<<sblocks, 256, 0, stream>>>(idx, flag, cur, buckets,
                                               n_edges, n_nodes, per_block);
    gemm_ab<<<782, 256, 0, stream>>>(X, WT, AB, n_nodes, n_tiles);
    edge_mlp<<<(NBUK * BCAP) / 128, 256, 0, stream>>>(
        AB, buckets, cur, b1f, W2PT, b2, out, n_edges);
}

// Round 8
// 156.311 us; speedup vs baseline: 1.1655x; 1.1130x over previous
//
#include <hip/hip_runtime.h>
#include <hip/hip_bf16.h>

// EdgePredictor: out[e] = relu(concat(X[row], X[col]) @ W1 + b1) @ W2 + b2
// Precompute per-node AB[n][256] = {X[n]@W1[:128,:] | X[n]@W1[128:,:]} in f16.
// Per edge: out = relu(A[row] + B[col] + b1) @ W2 + b2.
//
// R8: bucketing reverted (R6/R7 post-mortem: edge time == fabric bytes /
// 2.6 TB/s across 5 structural variants; bucketing conserved total fabric
// bytes — gather savings were eaten by randomized out-writes — while its
// scatter kernel cost 15-20us. Edge phase is at its structural floor:
// 128 MB irreducible random-line gather, ~62% L2 hit = agg-L2/table ratio.)
// gemm_ab change: xs/outs LDS buffers are time-disjoint within a tile ->
// union them (50KB -> 34KB, +1 barrier) for 3->4 blocks/CU drain overlap.

#define EMBED 128

typedef _Float16 half8 __attribute__((ext_vector_type(8)));
typedef _Float16 half4 __attribute__((ext_vector_type(4)));
typedef float floatx4 __attribute__((ext_vector_type(4)));

// --- Kernel 0: fused prep.
// Blocks 0..127: transpose+convert W1 (256x128 f32) -> WT (256x128 f16),
//   WT[j][k] = Wcat[k][j] (Wcat = [W1 top | W1 bottom] per concat split).
// Block 128: idx-mode ballot detect; W2PT[16][128] f16; b1f[128] f16.
__global__ __launch_bounds__(256) void prep(
    const float* __restrict__ W1, const float* __restrict__ W2,
    const float* __restrict__ b1, const int* __restrict__ idx,
    _Float16* __restrict__ WT, _Float16* __restrict__ W2PT,
    _Float16* __restrict__ b1f, int* __restrict__ flag) {
    if (blockIdx.x < 128) {
        __shared__ float lds[16][17];
        const int ty = threadIdx.x >> 4, tx = threadIdx.x & 15;
        const int r0 = (blockIdx.x >> 3) * 16;   // source W1 row tile
        const int c0 = (blockIdx.x & 7) * 16;    // source W1 col tile
        lds[ty][tx] = W1[(r0 + ty) * 128 + c0 + tx];
        __syncthreads();
        const int jbase = c0 + (r0 >= 128 ? 128 : 0);
        const int kbase = r0 & 127;
        WT[(size_t)(jbase + ty) * 128 + kbase + tx] = (_Float16)lds[tx][ty];
    } else {
        const int t = threadIdx.x;
        if (t < 64) {  // int64 layout iff first 64 high words are all zero
            const int hw = idx[2 * t + 1];
            const unsigned long long m = __ballot(hw != 0);
            if (t == 0) *flag = (m == 0ull) ? 1 : 0;
        }
        if (t < 128) b1f[t] = (_Float16)b1[t];
        for (int i = t; i < 2048; i += 256) {  // W2PT[n][k] = n<2 ? W2[k][n] : 0
            const int n = i >> 7, k = i & 127;
            W2PT[i] = (n < 2) ? (_Float16)W2[k * 2 + n] : (_Float16)0.f;
        }
    }
}

// --- Kernel 1: AB = [X | X] @ Wcat via f16 MFMA, operand-swapped
// (A-operand = W-frag so D rows are output cols). 64-node tiles; 4 waves,
// wave w covers output cols [w*64, w*64+64). xs (stage, stride 136) and
// outs (epilogue, stride 264) share one 34KB LDS union -> 4 blocks/CU.
__global__ __launch_bounds__(256) void gemm_ab(
    const float* __restrict__ X, const _Float16* __restrict__ WT,
    _Float16* __restrict__ AB, int n_nodes, int n_tiles) {
    __shared__ _Float16 sh[64 * 264];  // 33792 B union: xs(17408) / outs(33792)
    _Float16* xs   = sh;               // stride 136
    _Float16* outs = sh;               // stride 264
    const int t = threadIdx.x;
    const int w = t >> 6, lane = t & 63, lm = lane & 15, quad = lane >> 4;

    for (int T = blockIdx.x; T < n_tiles; T += gridDim.x) {
        const int mblk = T * 64;

        // Stage: 64 rows x 128 f32, coalesced float4 loads, convert once.
#pragma unroll
        for (int i = 0; i < 8; ++i) {
            const int flat = i * 1024 + t * 4;  // float index in 64x128 tile
            const int row = flat >> 7, col = flat & 127;
            int node = mblk + row;
            if (node > n_nodes - 1) node = n_nodes - 1;  // clamp; never stored
            const float4 v = *(const float4*)(X + (size_t)node * EMBED + col);
            half4 h;
            h[0] = (_Float16)v.x; h[1] = (_Float16)v.y;
            h[2] = (_Float16)v.z; h[3] = (_Float16)v.w;
            *(half4*)(xs + row * 136 + col) = h;
        }
        __syncthreads();  // S1: stage visible

        floatx4 acc[4][4];  // [mf: node tile][jf: col tile]
#pragma unroll
        for (int a = 0; a < 4; ++a)
#pragma unroll
            for (int b = 0; b < 4; ++b)
                acc[a][b] = (floatx4){0.f, 0.f, 0.f, 0.f};

#pragma unroll
        for (int ks = 0; ks < 4; ++ks) {
            const int k0 = ks * 32 + quad * 8;
            half8 xf[4];  // B-operand: B[k][n=lane&15] = Xf16[node mf*16+lm][k]
#pragma unroll
            for (int mf = 0; mf < 4; ++mf)
                xf[mf] = *(const half8*)(xs + (mf * 16 + lm) * 136 + k0);
#pragma unroll
            for (int jf = 0; jf < 4; ++jf) {
                const int j = w * 64 + jf * 16 + lm;  // A-op: WT row = out col
                const half8 wf = *(const half8*)(WT + (size_t)j * EMBED + k0);
#pragma unroll
                for (int mf = 0; mf < 4; ++mf)
                    acc[mf][jf] = __builtin_amdgcn_mfma_f32_16x16x32_f16(wf, xf[mf], acc[mf][jf], 0, 0, 0);
            }
        }
        __syncthreads();  // S2: all xs reads done before outs overwrites union

        // Pack D into LDS out tile: node-major [local node][j], stride 264.
        // D: col(lane&15) = node within mf-tile, row(quad*4+r) = output col j.
#pragma unroll
        for (int mf = 0; mf < 4; ++mf) {
#pragma unroll
            for (int jf = 0; jf < 4; ++jf) {
                half4 h;
#pragma unroll
                for (int r = 0; r < 4; ++r) h[r] = (_Float16)acc[mf][jf][r];
                *(half4*)(outs + (mf * 16 + lm) * 264 + w * 64 + jf * 16 + quad * 4) = h;
            }
        }
        __syncthreads();  // S3: outs visible

        // Coalesced store: 64 nodes x 512 B contiguous in AB (node-major).
#pragma unroll
        for (int i = 0; i < 8; ++i) {
            const int idx8 = i * 256 + t;         // half8 index in 64x256 tile
            const int node = idx8 >> 5, jj = idx8 & 31;
            if (mblk + node < n_nodes)
                *(half8*)(AB + (size_t)(mblk + node) * 256 + jj * 8) =
                    *(const half8*)(outs + node * 264 + jj * 8);
        }
        __syncthreads();  // S4: outs reads done before next tile's stage
    }
}

// --- Kernel 2: per-edge MLP, 32 edges/wave (2 MFMA groups), all gathers
// issued before compute. Lane l serves edges ebase+(l&15) and ebase+16+(l&15);
// gathers land directly in MFMA A-layout (A[m=lane&15][k=quad*8+j]).
__global__ __launch_bounds__(256) void edge_mlp(
    const _Float16* __restrict__ AB, const int* __restrict__ eidx,
    const int* __restrict__ flag, const _Float16* __restrict__ b1f,
    const _Float16* __restrict__ W2PT, const float* __restrict__ b2,
    float* __restrict__ out, int n_edges) {
    const int lane = threadIdx.x & 63, lm = lane & 15, quad = lane >> 4;
    const int ebase = (blockIdx.x * 4 + (threadIdx.x >> 6)) * 32;
    if (ebase >= n_edges) return;

    const int mode = *flag;  // wave-uniform
    int e0 = ebase + lm, e1 = ebase + 16 + lm;
    if (e0 > n_edges - 1) e0 = n_edges - 1;  // tail clamp; stores guarded
    if (e1 > n_edges - 1) e1 = n_edges - 1;
    int row0, col0, row1, col1;
    if (mode) {  // int64 layout: low word at int32 index 2*k
        row0 = eidx[2 * (size_t)e0];
        col0 = eidx[2 * ((size_t)n_edges + e0)];
        row1 = eidx[2 * (size_t)e1];
        col1 = eidx[2 * ((size_t)n_edges + e1)];
    } else {
        row0 = eidx[e0];
        col0 = eidx[(size_t)n_edges + e0];
        row1 = eidx[e1];
        col1 = eidx[(size_t)n_edges + e1];
    }

    const _Float16* a0p = AB + (size_t)row0 * 256;
    const _Float16* b0p = AB + (size_t)col0 * 256 + 128;
    const _Float16* a1p = AB + (size_t)row1 * 256;
    const _Float16* b1p = AB + (size_t)col1 * 256 + 128;

    // Issue all 16 gathers up front (each b128: 16 edges x one 64B line).
    half8 a0[4], b0[4], a1[4], b1[4];
#pragma unroll
    for (int ks = 0; ks < 4; ++ks) {
        const int k0 = ks * 32 + quad * 8;
        a0[ks] = *(const half8*)(a0p + k0);
        b0[ks] = *(const half8*)(b0p + k0);
        a1[ks] = *(const half8*)(a1p + k0);
        b1[ks] = *(const half8*)(b1p + k0);
    }

    floatx4 acc0 = (floatx4){0.f, 0.f, 0.f, 0.f};
    floatx4 acc1 = (floatx4){0.f, 0.f, 0.f, 0.f};
#pragma unroll
    for (int ks = 0; ks < 4; ++ks) {
        const int k0 = ks * 32 + quad * 8;
        const half8 bi = *(const half8*)(b1f + k0);          // wave-uniform
        const half8 wv = *(const half8*)(W2PT + lm * 128 + k0);
        half8 h0 = a0[ks] + b0[ks] + bi;
        half8 h1 = a1[ks] + b1[ks] + bi;
#pragma unroll
        for (int j = 0; j < 8; ++j) {
            h0[j] = h0[j] > (_Float16)0.f ? h0[j] : (_Float16)0.f;
            h1[j] = h1[j] > (_Float16)0.f ? h1[j] : (_Float16)0.f;
        }
        acc0 = __builtin_amdgcn_mfma_f32_16x16x32_f16(h0, wv, acc0, 0, 0, 0);
        acc1 = __builtin_amdgcn_mfma_f32_16x16x32_f16(h1, wv, acc1, 0, 0, 0);
    }

    if (lm < 2) {
        const float b2v = b2[lm];
#pragma unroll
        for (int r = 0; r < 4; ++r) {
            const int ed0 = ebase + quad * 4 + r;
            const int ed1 = ebase + 16 + quad * 4 + r;
            if (ed0 < n_edges) out[(size_t)ed0 * 2 + lm] = acc0[r] + b2v;
            if (ed1 < n_edges) out[(size_t)ed1 * 2 + lm] = acc1[r] + b2v;
        }
    }
}

extern "C" void kernel_launch(void* const* d_in, const int* in_sizes, int n_in,
                              void* d_out, int out_size, void* d_ws, size_t ws_size,
                              hipStream_t stream) {
    const float* X   = (const float*)d_in[0];
    const int*   idx = (const int*)d_in[1];
    const float* W1  = (const float*)d_in[2];
    const float* b1  = (const float*)d_in[3];
    const float* W2  = (const float*)d_in[4];
    const float* b2  = (const float*)d_in[5];
    float* out = (float*)d_out;

    const int n_nodes = in_sizes[0] / EMBED;   // 100000
    const int n_edges = in_sizes[1] / 2;       // 500000

    // ws: flag @0 | AB @256 (n_nodes*256*2 B) | WT (64KB) | W2PT (4KB) | b1f (256B)
    char* ws = (char*)d_ws;
    int*      flag = (int*)ws;
    _Float16* AB   = (_Float16*)(ws + 256);
    _Float16* WT   = (_Float16*)(ws + 256 + (size_t)n_nodes * 512);
    _Float16* W2PT = WT + 256 * 128;
    _Float16* b1f  = W2PT + 16 * 128;

    const int n_tiles = (n_nodes + 63) / 64;   // 1563

    prep<<<129, 256, 0, stream>>>(W1, W2, b1, idx, WT, W2PT, b1f, flag);
    gemm_ab<<<n_tiles, 256, 0, stream>>>(X, WT, AB, n_nodes, n_tiles);
    edge_mlp<<<(n_edges + 127) / 128, 256, 0, stream>>>(
        AB, idx, flag, b1f, W2PT, b2, out, n_edges);
}

// Round 9
// 153.358 us; speedup vs baseline: 1.1879x; 1.0193x over previous
//
#include <hip/hip_runtime.h>
#include <hip/hip_bf16.h>

// EdgePredictor: out[e] = relu(concat(X[row], X[col]) @ W1 + b1) @ W2 + b2
// Precompute per-node AB[n][256] = {X[n]@W1[:128,:] | X[n]@W1[128:,:]} in f16.
// Per edge: out = relu(A[row] + B[col] + b1) @ W2 + b2.
//
// R9 (single-variable: gemm_ab only; edge/prep untouched): gemm sits at
// ~35-38us vs ~16-20us streaming floor while issue math says ~3us — the
// fitting mechanism is a cold ~900cyc HBM load chain at each tile top,
// serialized against compute (only 4 short blocks/CU of TLP). Fix:
// grid-stride 782 blocks (R5 config, 2 tiles/block) + REGISTER PREFETCH —
// next tile's 8 float4 X loads issue right after S1, overlapping the
// current tile's MFMA+epilogue. Edge floor reconfirmed (6 variants ~50us).

#define EMBED 128

typedef _Float16 half8 __attribute__((ext_vector_type(8)));
typedef _Float16 half4 __attribute__((ext_vector_type(4)));
typedef float floatx4 __attribute__((ext_vector_type(4)));

// --- Kernel 0: fused prep.
// Blocks 0..127: transpose+convert W1 (256x128 f32) -> WT (256x128 f16),
//   WT[j][k] = Wcat[k][j] (Wcat = [W1 top | W1 bottom] per concat split).
// Block 128: idx-mode ballot detect; W2PT[16][128] f16; b1f[128] f16.
__global__ __launch_bounds__(256) void prep(
    const float* __restrict__ W1, const float* __restrict__ W2,
    const float* __restrict__ b1, const int* __restrict__ idx,
    _Float16* __restrict__ WT, _Float16* __restrict__ W2PT,
    _Float16* __restrict__ b1f, int* __restrict__ flag) {
    if (blockIdx.x < 128) {
        __shared__ float lds[16][17];
        const int ty = threadIdx.x >> 4, tx = threadIdx.x & 15;
        const int r0 = (blockIdx.x >> 3) * 16;   // source W1 row tile
        const int c0 = (blockIdx.x & 7) * 16;    // source W1 col tile
        lds[ty][tx] = W1[(r0 + ty) * 128 + c0 + tx];
        __syncthreads();
        const int jbase = c0 + (r0 >= 128 ? 128 : 0);
        const int kbase = r0 & 127;
        WT[(size_t)(jbase + ty) * 128 + kbase + tx] = (_Float16)lds[tx][ty];
    } else {
        const int t = threadIdx.x;
        if (t < 64) {  // int64 layout iff first 64 high words are all zero
            const int hw = idx[2 * t + 1];
            const unsigned long long m = __ballot(hw != 0);
            if (t == 0) *flag = (m == 0ull) ? 1 : 0;
        }
        if (t < 128) b1f[t] = (_Float16)b1[t];
        for (int i = t; i < 2048; i += 256) {  // W2PT[n][k] = n<2 ? W2[k][n] : 0
            const int n = i >> 7, k = i & 127;
            W2PT[i] = (n < 2) ? (_Float16)W2[k * 2 + n] : (_Float16)0.f;
        }
    }
}

// --- Kernel 1: AB = [X | X] @ Wcat via f16 MFMA, operand-swapped
// (A-operand = W-frag so D rows are output cols). Grid-stride, 2 tiles per
// block; next tile's X loads prefetched into registers during compute.
// xs (stage, stride 136) and outs (epilogue, stride 264) share 34KB LDS.
__global__ __launch_bounds__(256) void gemm_ab(
    const float* __restrict__ X, const _Float16* __restrict__ WT,
    _Float16* __restrict__ AB, int n_nodes, int n_tiles) {
    __shared__ _Float16 sh[64 * 264];  // 33792 B union: xs(17408) / outs(33792)
    _Float16* xs   = sh;               // stride 136
    _Float16* outs = sh;               // stride 264
    const int t = threadIdx.x;
    const int w = t >> 6, lane = t & 63, lm = lane & 15, quad = lane >> 4;

    // Per-thread stage coordinates (fixed across tiles).
    int srow[8], scol[8];
#pragma unroll
    for (int i = 0; i < 8; ++i) {
        const int flat = i * 1024 + t * 4;
        srow[i] = flat >> 7;
        scol[i] = flat & 127;
    }

    int T = blockIdx.x;
    float4 pf[8];
    if (T < n_tiles) {  // prefetch first tile
#pragma unroll
        for (int i = 0; i < 8; ++i) {
            int node = T * 64 + srow[i];
            if (node > n_nodes - 1) node = n_nodes - 1;  // clamp; never stored
            pf[i] = *(const float4*)(X + (size_t)node * EMBED + scol[i]);
        }
    }

    for (; T < n_tiles; T += gridDim.x) {
        const int mblk = T * 64;

        // Stage: spill prefetched registers to LDS (convert f32->f16 once).
#pragma unroll
        for (int i = 0; i < 8; ++i) {
            half4 h;
            h[0] = (_Float16)pf[i].x; h[1] = (_Float16)pf[i].y;
            h[2] = (_Float16)pf[i].z; h[3] = (_Float16)pf[i].w;
            *(half4*)(xs + srow[i] * 136 + scol[i]) = h;
        }
        __syncthreads();  // S1: stage visible

        // Prefetch next tile NOW — loads overlap this tile's MFMA+epilogue.
        const int Tn = T + gridDim.x;
        if (Tn < n_tiles) {
#pragma unroll
            for (int i = 0; i < 8; ++i) {
                int node = Tn * 64 + srow[i];
                if (node > n_nodes - 1) node = n_nodes - 1;
                pf[i] = *(const float4*)(X + (size_t)node * EMBED + scol[i]);
            }
        }

        floatx4 acc[4][4];  // [mf: node tile][jf: col tile]
#pragma unroll
        for (int a = 0; a < 4; ++a)
#pragma unroll
            for (int b = 0; b < 4; ++b)
                acc[a][b] = (floatx4){0.f, 0.f, 0.f, 0.f};

#pragma unroll
        for (int ks = 0; ks < 4; ++ks) {
            const int k0 = ks * 32 + quad * 8;
            half8 xf[4];  // B-operand: B[k][n=lane&15] = Xf16[node mf*16+lm][k]
#pragma unroll
            for (int mf = 0; mf < 4; ++mf)
                xf[mf] = *(const half8*)(xs + (mf * 16 + lm) * 136 + k0);
#pragma unroll
            for (int jf = 0; jf < 4; ++jf) {
                const int j = w * 64 + jf * 16 + lm;  // A-op: WT row = out col
                const half8 wf = *(const half8*)(WT + (size_t)j * EMBED + k0);
#pragma unroll
                for (int mf = 0; mf < 4; ++mf)
                    acc[mf][jf] = __builtin_amdgcn_mfma_f32_16x16x32_f16(wf, xf[mf], acc[mf][jf], 0, 0, 0);
            }
        }
        __syncthreads();  // S2: xs reads done before outs overwrites union

        // Pack D into LDS out tile: node-major [local node][j], stride 264.
        // D: col(lane&15) = node within mf-tile, row(quad*4+r) = output col j.
#pragma unroll
        for (int mf = 0; mf < 4; ++mf) {
#pragma unroll
            for (int jf = 0; jf < 4; ++jf) {
                half4 h;
#pragma unroll
                for (int r = 0; r < 4; ++r) h[r] = (_Float16)acc[mf][jf][r];
                *(half4*)(outs + (mf * 16 + lm) * 264 + w * 64 + jf * 16 + quad * 4) = h;
            }
        }
        __syncthreads();  // S3: outs visible

        // Coalesced store: 64 nodes x 512 B contiguous in AB (node-major).
#pragma unroll
        for (int i = 0; i < 8; ++i) {
            const int idx8 = i * 256 + t;         // half8 index in 64x256 tile
            const int node = idx8 >> 5, jj = idx8 & 31;
            if (mblk + node < n_nodes)
                *(half8*)(AB + (size_t)(mblk + node) * 256 + jj * 8) =
                    *(const half8*)(outs + node * 264 + jj * 8);
        }
        __syncthreads();  // S4: outs reads done before next tile's stage
    }
}

// --- Kernel 2: per-edge MLP, 32 edges/wave (2 MFMA groups), all gathers
// issued before compute. Lane l serves edges ebase+(l&15) and ebase+16+(l&15);
// gathers land directly in MFMA A-layout (A[m=lane&15][k=quad*8+j]).
__global__ __launch_bounds__(256) void edge_mlp(
    const _Float16* __restrict__ AB, const int* __restrict__ eidx,
    const int* __restrict__ flag, const _Float16* __restrict__ b1f,
    const _Float16* __restrict__ W2PT, const float* __restrict__ b2,
    float* __restrict__ out, int n_edges) {
    const int lane = threadIdx.x & 63, lm = lane & 15, quad = lane >> 4;
    const int ebase = (blockIdx.x * 4 + (threadIdx.x >> 6)) * 32;
    if (ebase >= n_edges) return;

    const int mode = *flag;  // wave-uniform
    int e0 = ebase + lm, e1 = ebase + 16 + lm;
    if (e0 > n_edges - 1) e0 = n_edges - 1;  // tail clamp; stores guarded
    if (e1 > n_edges - 1) e1 = n_edges - 1;
    int row0, col0, row1, col1;
    if (mode) {  // int64 layout: low word at int32 index 2*k
        row0 = eidx[2 * (size_t)e0];
        col0 = eidx[2 * ((size_t)n_edges + e0)];
        row1 = eidx[2 * (size_t)e1];
        col1 = eidx[2 * ((size_t)n_edges + e1)];
    } else {
        row0 = eidx[e0];
        col0 = eidx[(size_t)n_edges + e0];
        row1 = eidx[e1];
        col1 = eidx[(size_t)n_edges + e1];
    }

    const _Float16* a0p = AB + (size_t)row0 * 256;
    const _Float16* b0p = AB + (size_t)col0 * 256 + 128;
    const _Float16* a1p = AB + (size_t)row1 * 256;
    const _Float16* b1p = AB + (size_t)col1 * 256 + 128;

    // Issue all 16 gathers up front (each b128: 16 edges x one 64B line).
    half8 a0[4], b0[4], a1[4], b1[4];
#pragma unroll
    for (int ks = 0; ks < 4; ++ks) {
        const int k0 = ks * 32 + quad * 8;
        a0[ks] = *(const half8*)(a0p + k0);
        b0[ks] = *(const half8*)(b0p + k0);
        a1[ks] = *(const half8*)(a1p + k0);
        b1[ks] = *(const half8*)(b1p + k0);
    }

    floatx4 acc0 = (floatx4){0.f, 0.f, 0.f, 0.f};
    floatx4 acc1 = (floatx4){0.f, 0.f, 0.f, 0.f};
#pragma unroll
    for (int ks = 0; ks < 4; ++ks) {
        const int k0 = ks * 32 + quad * 8;
        const half8 bi = *(const half8*)(b1f + k0);          // wave-uniform
        const half8 wv = *(const half8*)(W2PT + lm * 128 + k0);
        half8 h0 = a0[ks] + b0[ks] + bi;
        half8 h1 = a1[ks] + b1[ks] + bi;
#pragma unroll
        for (int j = 0; j < 8; ++j) {
            h0[j] = h0[j] > (_Float16)0.f ? h0[j] : (_Float16)0.f;
            h1[j] = h1[j] > (_Float16)0.f ? h1[j] : (_Float16)0.f;
        }
        acc0 = __builtin_amdgcn_mfma_f32_16x16x32_f16(h0, wv, acc0, 0, 0, 0);
        acc1 = __builtin_amdgcn_mfma_f32_16x16x32_f16(h1, wv, acc1, 0, 0, 0);
    }

    if (lm < 2) {
        const float b2v = b2[lm];
#pragma unroll
        for (int r = 0; r < 4; ++r) {
            const int ed0 = ebase + quad * 4 + r;
            const int ed1 = ebase + 16 + quad * 4 + r;
            if (ed0 < n_edges) out[(size_t)ed0 * 2 + lm] = acc0[r] + b2v;
            if (ed1 < n_edges) out[(size_t)ed1 * 2 + lm] = acc1[r] + b2v;
        }
    }
}

extern "C" void kernel_launch(void* const* d_in, const int* in_sizes, int n_in,
                              void* d_out, int out_size, void* d_ws, size_t ws_size,
                              hipStream_t stream) {
    const float* X   = (const float*)d_in[0];
    const int*   idx = (const int*)d_in[1];
    const float* W1  = (const float*)d_in[2];
    const float* b1  = (const float*)d_in[3];
    const float* W2  = (const float*)d_in[4];
    const float* b2  = (const float*)d_in[5];
    float* out = (float*)d_out;

    const int n_nodes = in_sizes[0] / EMBED;   // 100000
    const int n_edges = in_sizes[1] / 2;       // 500000

    // ws: flag @0 | AB @256 (n_nodes*256*2 B) | WT (64KB) | W2PT (4KB) | b1f (256B)
    char* ws = (char*)d_ws;
    int*      flag = (int*)ws;
    _Float16* AB   = (_Float16*)(ws + 256);
    _Float16* WT   = (_Float16*)(ws + 256 + (size_t)n_nodes * 512);
    _Float16* W2PT = WT + 256 * 128;
    _Float16* b1f  = W2PT + 16 * 128;

    const int n_tiles = (n_nodes + 63) / 64;   // 1563

    prep<<<129, 256, 0, stream>>>(W1, W2, b1, idx, WT, W2PT, b1f, flag);
    gemm_ab<<<782, 256, 0, stream>>>(X, WT, AB, n_nodes, n_tiles);
    edge_mlp<<<(n_edges + 127) / 128, 256, 0, stream>>>(
        AB, idx, flag, b1f, W2PT, b2, out, n_edges);
}